// Round 1
// baseline (269.742 us; speedup 1.0000x reference)
//
#include <hip/hip_runtime.h>

// AveragePoolingClassLoss on MI355X.
// logits: [32, 6, 512, 512] fp32; class_gt: [32, 5] fp32; out: scalar fp32.
//
// Math reduction:
//   argmax over softmax(ch 0..4) == argmax over logits(ch 0..4)   (monotone)
//   s[b,c]  = sum over pixels with argmax==c of p_max,  p_max = 1/sum_c exp(l_c - m)
//   cnt[b,c]= count of pixels with argmax==c
//   agg = cnt>0 ? s/cnt : 0 ;  loss = -mean(gt*max(log agg,-100)+(1-gt)*max(log1p(-agg),-100))

constexpr int NC   = 5;            // foreground classes
constexpr int NCH  = 6;            // channels in input (last = background, unread)
constexpr int HWSZ = 512 * 512;    // pixels per image
constexpr int NB   = 32;           // batch
constexpr int PIX_PER_BLOCK = 4096;
constexpr int BLOCKS_PER_IMG = HWSZ / PIX_PER_BLOCK;  // 64
// ws layout: per image b, 10 floats: [s_0..s_4, n_0..n_4] at ws[b*10 + i]

__global__ __launch_bounds__(256) void pool_kernel(const float* __restrict__ logits,
                                                   float* __restrict__ ws) {
    const int b     = blockIdx.x / BLOCKS_PER_IMG;
    const int chunk = blockIdx.x % BLOCKS_PER_IMG;
    const float* base = logits + (size_t)b * NCH * HWSZ + (size_t)chunk * PIX_PER_BLOCK;

    float s_loc[NC] = {0.f, 0.f, 0.f, 0.f, 0.f};
    float n_loc[NC] = {0.f, 0.f, 0.f, 0.f, 0.f};

    // 256 threads * 4 pixels (float4) * 4 iters = 4096 pixels
    #pragma unroll
    for (int it = 0; it < PIX_PER_BLOCK / (256 * 4); ++it) {
        const int pix = it * 1024 + threadIdx.x * 4;
        float4 v[NC];
        #pragma unroll
        for (int c = 0; c < NC; ++c)
            v[c] = *(const float4*)(base + (size_t)c * HWSZ + pix);

        #pragma unroll
        for (int j = 0; j < 4; ++j) {
            float l[NC];
            #pragma unroll
            for (int c = 0; c < NC; ++c)
                l[c] = reinterpret_cast<const float*>(&v[c])[j];

            // argmax, lowest index wins ties (strict >)
            float m = l[0];
            int mi = 0;
            #pragma unroll
            for (int c = 1; c < NC; ++c) {
                if (l[c] > m) { m = l[c]; mi = c; }
            }
            // p_max = 1 / sum exp(l - m)
            float den = 0.f;
            #pragma unroll
            for (int c = 0; c < NC; ++c)
                den += __expf(l[c] - m);
            const float p = 1.0f / den;

            // branchless scatter into the 5 bins (no dynamic register indexing)
            #pragma unroll
            for (int c = 0; c < NC; ++c) {
                const bool hit = (mi == c);
                s_loc[c] += hit ? p   : 0.f;
                n_loc[c] += hit ? 1.f : 0.f;
            }
        }
    }

    // wave(64)-level shuffle reduce, then LDS, then one global atomic per bin
    __shared__ float sh[2 * NC];
    if (threadIdx.x < 2 * NC) sh[threadIdx.x] = 0.f;
    __syncthreads();

    #pragma unroll
    for (int c = 0; c < NC; ++c) {
        float v = s_loc[c];
        float n = n_loc[c];
        #pragma unroll
        for (int off = 32; off > 0; off >>= 1) {
            v += __shfl_down(v, off);
            n += __shfl_down(n, off);
        }
        if ((threadIdx.x & 63) == 0) {
            atomicAdd(&sh[c], v);
            atomicAdd(&sh[NC + c], n);
        }
    }
    __syncthreads();
    if (threadIdx.x < 2 * NC)
        atomicAdd(&ws[b * 2 * NC + threadIdx.x], sh[threadIdx.x]);
}

__global__ __launch_bounds__(256) void loss_kernel(const float* __restrict__ ws,
                                                   const float* __restrict__ gt,
                                                   float* __restrict__ out) {
    const int tid = threadIdx.x;
    float contrib = 0.f;
    if (tid < NB * NC) {
        const int b = tid / NC;
        const int c = tid % NC;
        const float s = ws[b * 2 * NC + c];
        const float n = ws[b * 2 * NC + NC + c];
        const float agg = (n > 0.f) ? (s / fmaxf(n, 1.f)) : 0.f;
        // logf(0) = -inf -> clamped to -100, matching torch BCELoss / jnp reference
        const float lp  = fmaxf(logf(agg),    -100.f);
        const float l1  = fmaxf(log1pf(-agg), -100.f);
        const float g = gt[tid];
        contrib = g * lp + (1.f - g) * l1;
    }

    __shared__ float sh[4];
    float v = contrib;
    #pragma unroll
    for (int off = 32; off > 0; off >>= 1)
        v += __shfl_down(v, off);
    if ((tid & 63) == 0) sh[tid >> 6] = v;
    __syncthreads();
    if (tid == 0) {
        const float total = sh[0] + sh[1] + sh[2] + sh[3];
        out[0] = -total / (float)(NB * NC);
    }
}

extern "C" void kernel_launch(void* const* d_in, const int* in_sizes, int n_in,
                              void* d_out, int out_size, void* d_ws, size_t ws_size,
                              hipStream_t stream) {
    const float* logits = (const float*)d_in[0];
    const float* gt     = (const float*)d_in[1];
    float* out = (float*)d_out;
    float* ws  = (float*)d_ws;

    // ws is poisoned 0xAA before every call; zero the 1280 bytes we use.
    hipMemsetAsync(ws, 0, NB * 2 * NC * sizeof(float), stream);

    pool_kernel<<<NB * BLOCKS_PER_IMG, 256, 0, stream>>>(logits, ws);
    loss_kernel<<<1, 256, 0, stream>>>(ws, gt, out);
}

// Round 2
// 269.053 us; speedup vs baseline: 1.0026x; 1.0026x over previous
//
#include <hip/hip_runtime.h>

// AveragePoolingClassLoss on MI355X.
// logits: [32, 6, 512, 512] fp32; class_gt: [32, 5] fp32; out: scalar fp32.
//
// Math reduction:
//   argmax over softmax(ch 0..4) == argmax over logits(ch 0..4)   (monotone)
//   s[b,c]  = sum over pixels with argmax==c of p_max,  p_max = 1/sum_c exp(l_c - m)
//   cnt[b,c]= count of pixels with argmax==c
//   agg = cnt>0 ? s/cnt : 0 ;  loss = -mean(gt*max(log agg,-100)+(1-gt)*max(log1p(-agg),-100))
//
// Structure (2 dispatches, no ws zero-init needed):
//   pool_kernel:  2048 blocks; each block writes 10 partial floats unconditionally
//                 to its own ws slot (no atomics, no memset dependency).
//   loss_kernel:  reduces 2048x10 partials (80 KB, L2-resident) + BCE -> scalar.

constexpr int NC   = 5;            // foreground classes
constexpr int NCH  = 6;            // channels in input (last = background, unread)
constexpr int HWSZ = 512 * 512;    // pixels per image
constexpr int NB   = 32;           // batch
constexpr int PIX_PER_BLOCK = 4096;
constexpr int BLOCKS_PER_IMG = HWSZ / PIX_PER_BLOCK;  // 64
constexpr int NBLK = NB * BLOCKS_PER_IMG;             // 2048
// ws layout: block g writes ws[g*10 + (0..4)] = s_c, ws[g*10 + (5..9)] = cnt_c

__global__ __launch_bounds__(256) void pool_kernel(const float* __restrict__ logits,
                                                   float* __restrict__ ws) {
    const int b     = blockIdx.x / BLOCKS_PER_IMG;
    const int chunk = blockIdx.x % BLOCKS_PER_IMG;
    const float* base = logits + (size_t)b * NCH * HWSZ + (size_t)chunk * PIX_PER_BLOCK;

    float s_loc[NC] = {0.f, 0.f, 0.f, 0.f, 0.f};
    float n_loc[NC] = {0.f, 0.f, 0.f, 0.f, 0.f};

    // 256 threads * 4 pixels (float4) * 4 iters = 4096 pixels
    #pragma unroll
    for (int it = 0; it < PIX_PER_BLOCK / (256 * 4); ++it) {
        const int pix = it * 1024 + threadIdx.x * 4;
        float4 v[NC];
        #pragma unroll
        for (int c = 0; c < NC; ++c)
            v[c] = *(const float4*)(base + (size_t)c * HWSZ + pix);

        #pragma unroll
        for (int j = 0; j < 4; ++j) {
            float l[NC];
            #pragma unroll
            for (int c = 0; c < NC; ++c)
                l[c] = reinterpret_cast<const float*>(&v[c])[j];

            // argmax, lowest index wins ties (strict >)
            float m = l[0];
            int mi = 0;
            #pragma unroll
            for (int c = 1; c < NC; ++c) {
                if (l[c] > m) { m = l[c]; mi = c; }
            }
            // p_max = 1 / sum exp(l - m); raw v_rcp is plenty accurate here
            float den = 0.f;
            #pragma unroll
            for (int c = 0; c < NC; ++c)
                den += __expf(l[c] - m);
            const float p = __builtin_amdgcn_rcpf(den);

            // branchless scatter into the 5 bins (no dynamic register indexing)
            #pragma unroll
            for (int c = 0; c < NC; ++c) {
                const bool hit = (mi == c);
                s_loc[c] += hit ? p   : 0.f;
                n_loc[c] += hit ? 1.f : 0.f;
            }
        }
    }

    // wave(64)-level shuffle reduce -> per-wave LDS slots -> 10 plain stores
    __shared__ float sh[4][2 * NC];
    const int wave = threadIdx.x >> 6;

    #pragma unroll
    for (int c = 0; c < NC; ++c) {
        float v = s_loc[c];
        float n = n_loc[c];
        #pragma unroll
        for (int off = 32; off > 0; off >>= 1) {
            v += __shfl_down(v, off);
            n += __shfl_down(n, off);
        }
        if ((threadIdx.x & 63) == 0) {
            sh[wave][c]      = v;
            sh[wave][NC + c] = n;
        }
    }
    __syncthreads();
    if (threadIdx.x < 2 * NC) {
        const float t = sh[0][threadIdx.x] + sh[1][threadIdx.x] +
                        sh[2][threadIdx.x] + sh[3][threadIdx.x];
        ws[(size_t)blockIdx.x * 2 * NC + threadIdx.x] = t;  // unconditional: no init needed
    }
}

__global__ __launch_bounds__(256) void loss_kernel(const float* __restrict__ ws,
                                                   const float* __restrict__ gt,
                                                   float* __restrict__ out) {
    const int tid = threadIdx.x;
    float contrib = 0.f;
    if (tid < NB * NC) {
        const int b = tid / NC;
        const int c = tid % NC;
        float s = 0.f, n = 0.f;
        #pragma unroll 8
        for (int k = 0; k < BLOCKS_PER_IMG; ++k) {
            const float* p = ws + ((size_t)(b * BLOCKS_PER_IMG + k)) * 2 * NC;
            s += p[c];
            n += p[NC + c];
        }
        const float agg = (n > 0.f) ? (s / fmaxf(n, 1.f)) : 0.f;
        // logf(0) = -inf -> clamped to -100, matching torch BCELoss / jnp reference
        const float lp  = fmaxf(logf(agg),    -100.f);
        const float l1  = fmaxf(log1pf(-agg), -100.f);
        const float g = gt[tid];
        contrib = g * lp + (1.f - g) * l1;
    }

    __shared__ float sh[4];
    float v = contrib;
    #pragma unroll
    for (int off = 32; off > 0; off >>= 1)
        v += __shfl_down(v, off);
    if ((tid & 63) == 0) sh[tid >> 6] = v;
    __syncthreads();
    if (tid == 0) {
        const float total = sh[0] + sh[1] + sh[2] + sh[3];
        out[0] = -total / (float)(NB * NC);
    }
}

extern "C" void kernel_launch(void* const* d_in, const int* in_sizes, int n_in,
                              void* d_out, int out_size, void* d_ws, size_t ws_size,
                              hipStream_t stream) {
    const float* logits = (const float*)d_in[0];
    const float* gt     = (const float*)d_in[1];
    float* out = (float*)d_out;
    float* ws  = (float*)d_ws;   // 2048*10 floats = 80 KB used, all written before read

    pool_kernel<<<NBLK, 256, 0, stream>>>(logits, ws);
    loss_kernel<<<1, 256, 0, stream>>>(ws, gt, out);
}